// Round 3
// baseline (600.829 us; speedup 1.0000x reference)
//
#include <hip/hip_runtime.h>
#include <hip/hip_bf16.h>
#include <stdint.h>

typedef __attribute__((ext_vector_type(8))) __bf16 bf16x8;
typedef __attribute__((ext_vector_type(4))) float f32x4;

#define DEVINL static __device__ __forceinline__

constexpr int WSZ = 7, EXPAND = 3, NHEAD = 12, DIM = 384, HDIM = 32;
constexpr int WS2 = 49, NKEY = 132, NTOK = 181, NTOKP = 192;
constexpr int BB = 2, HH = 168, WW = 168;
constexpr int NWY = HH / WSZ, NWX = WW / WSZ;        // 24, 24
constexpr int NWIN = BB * NWY * NWX;                 // 1152
constexpr int MTOT = BB * HH * WW;                   // 56448
constexpr float SCALE = 0.1767766952966369f;         // 32^-0.5

// ---- neighbor offset table (replicates _valid_ind_rolled order) ----
struct NbrTab { int dy[NKEY]; int dx[NKEY]; };
constexpr NbrTab make_nbr() {
  NbrTab t{};
  int n = 0;
  for (int quad = 0; quad < 4; ++quad)
    for (int i = 0; i < WSZ; ++i)
      for (int j = 0; j < WSZ; ++j) {
        bool drop;
        if (quad == 0)      drop = (i < WSZ - EXPAND) && (j < WSZ - EXPAND);
        else if (quad == 1) drop = (i < WSZ - EXPAND) && (j >= EXPAND);
        else if (quad == 2) drop = (i >= EXPAND)      && (j < WSZ - EXPAND);
        else                drop = (i >= EXPAND)      && (j >= EXPAND);
        if (!drop) {
          t.dy[n] = (quad < 2)        ? i + EXPAND : i - EXPAND;
          t.dx[n] = ((quad & 1) == 0) ? j + EXPAND : j - EXPAND;
          ++n;
        }
      }
  return t;
}
__device__ constexpr NbrTab NTAB = make_nbr();

// pixel-row -> window-ordered row permutation
DEVINL int qperm(int m) {
  int b = m / (HH * WW);
  int rem = m - b * (HH * WW);
  int y = rem / WW;
  int x = rem - y * WW;
  int win = b * (NWY * NWX) + (y / WSZ) * NWX + (x / WSZ);
  int qi = (y % WSZ) * WSZ + (x % WSZ);
  return win * WS2 + qi;
}

DEVINL bf16x8 load8_cvt(const float* p) {
  float4 a = *(const float4*)p;
  float4 b = *(const float4*)(p + 4);
  bf16x8 r = {(__bf16)a.x, (__bf16)a.y, (__bf16)a.z, (__bf16)a.w,
              (__bf16)b.x, (__bf16)b.y, (__bf16)b.z, (__bf16)b.w};
  return r;
}
DEVINL bf16x8 load8_cvt(const __bf16* p) { return *(const bf16x8*)p; }

// ---- GEMM: out[m][n] = sum_k A[m][k] * Bt[n][k] + bias[n] ----
// A: f32 or bf16 (converted to bf16 in LDS). Bt/bias: f32. Out: bf16 or f32.
// 128x128 tile, BK=64, 4 waves (2x2), each wave 64x64 = 4x4 frags of 16x16x32.
// qPerm: when set, rows of output 0 (sel==0) are permuted pixel->window order.
template <typename AT, typename OT>
__global__ __launch_bounds__(256) void gemm_bt(
    const AT* __restrict__ A, const float* __restrict__ Bt,
    const float* __restrict__ bias,
    OT* __restrict__ O0, OT* __restrict__ O1, OT* __restrict__ O2,
    int K, int NoutPer, int qPerm) {
  __shared__ __bf16 As[128 * 64];
  __shared__ __bf16 Bs[128 * 64];

  const int t = threadIdx.x;
  const int wv = t >> 6, ln = t & 63;
  const int lc = ln & 15, kg = (ln >> 4) * 8;
  const int wm = wv >> 1, wn = wv & 1;
  const int m0 = blockIdx.y * 128, n0 = blockIdx.x * 128;
  const int srow = t >> 3, scol = (t & 7) * 8;

  f32x4 acc[4][4] = {};

  for (int kt = 0; kt < K; kt += 64) {
#pragma unroll
    for (int i = 0; i < 4; ++i) {
      int row = i * 32 + srow;
      bf16x8 av = load8_cvt(A + (size_t)(m0 + row) * K + kt + scol);
      *(bf16x8*)&As[row * 64 + scol] = av;
      bf16x8 bv = load8_cvt(Bt + (size_t)(n0 + row) * K + kt + scol);
      *(bf16x8*)&Bs[row * 64 + scol] = bv;
    }
    __syncthreads();
#pragma unroll
    for (int ks = 0; ks < 2; ++ks) {
      bf16x8 af[4], bb[4];
#pragma unroll
      for (int m = 0; m < 4; ++m)
        af[m] = *(const bf16x8*)&As[(wm * 64 + m * 16 + lc) * 64 + ks * 32 + kg];
#pragma unroll
      for (int n = 0; n < 4; ++n)
        bb[n] = *(const bf16x8*)&Bs[(wn * 64 + n * 16 + lc) * 64 + ks * 32 + kg];
#pragma unroll
      for (int m = 0; m < 4; ++m)
#pragma unroll
        for (int n = 0; n < 4; ++n)
          acc[m][n] = __builtin_amdgcn_mfma_f32_16x16x32_bf16(af[m], bb[n], acc[m][n], 0, 0, 0);
    }
    __syncthreads();
  }

  OT* outs[3] = {O0, O1, O2};
#pragma unroll
  for (int n = 0; n < 4; ++n) {
    int col = n0 + wn * 64 + n * 16 + lc;
    int sel = col / NoutPer;
    int c = col - sel * NoutPer;
    float bv = bias[col];
    OT* op = outs[sel];
    bool perm = qPerm && (sel == 0);
#pragma unroll
    for (int m = 0; m < 4; ++m) {
      int row = m0 + wm * 64 + m * 16 + (ln >> 4) * 4;
#pragma unroll
      for (int r = 0; r < 4; ++r) {
        int rr = row + r;
        int orow = perm ? qperm(rr) : rr;
        op[(size_t)orow * NoutPer + c] = (OT)(acc[m][n][r] + bv);
      }
    }
  }
}

// ---- attention: one block per (window, head), 4 waves ----
// Qg is WINDOW-ordered (rows win*49+q); Kg/Vg are pixel-ordered bf16 planes.
// Og aliases Qg (safe: each block writes exactly the rows x head-cols it read).
__global__ __launch_bounds__(256) void attn_win(
    const __bf16* __restrict__ Qg, const __bf16* __restrict__ Kg, const __bf16* __restrict__ Vg,
    const float* __restrict__ rpbT, const float* __restrict__ rpbN,
    __bf16* __restrict__ Og) {
  __shared__ __bf16 Qs[64 * 40];    // q tokens (pad>=49 zero), 32 dims, stride 40
  __shared__ __bf16 Ks[192 * 40];   // key tokens (pad>=181 zero)
  __shared__ __bf16 Vt[32 * 200];   // V transposed: [dim][token], stride 200
  __shared__ __bf16 Ps[64 * 200];   // softmax probs [q][token]
  __shared__ int tokOff[NTOKP];

  const int win = blockIdx.x;
  const int h = blockIdx.y;
  const int b = win / (NWY * NWX);
  const int wrem = win - b * (NWY * NWX);
  const int wy = wrem / NWX, wx = wrem - wy * NWX;
  const int y0 = wy * WSZ, x0 = wx * WSZ;

  const int t = threadIdx.x;
  const int wv = t >> 6, ln = t & 63;
  const int lc = ln & 15, lg = ln >> 4;

  if (t < NTOKP) {
    int yy = 0, xx = 0;
    if (t < WS2) { yy = y0 + t / WSZ; xx = x0 + t % WSZ; }
    else if (t < NTOK) {
      int j = t - WS2;
      yy = y0 + NTAB.dy[j]; xx = x0 + NTAB.dx[j];
      if (yy < 0) yy += HH; else if (yy >= HH) yy -= HH;
      if (xx < 0) xx += WW; else if (xx >= WW) xx -= WW;
    }
    tokOff[t] = ((b * HH + yy) * WW + xx) * DIM;
  }
  __syncthreads();

  const int hb = h * HDIM;

  { // stage Q (window-ordered source): 64 tokens x 32 dims
    int token = t >> 2, ch = t & 3;
    bf16x8 v = {};
    if (token < WS2)
      v = *(const bf16x8*)(Qg + (size_t)(win * WS2 + token) * DIM + hb + ch * 8);
    *(bf16x8*)&Qs[token * 40 + ch * 8] = v;
  }
#pragma unroll
  for (int it = 0; it < 3; ++it) { // stage K and V^T: 192 tokens x 4 chunks
    int idx = t + it * 256;
    int token = idx >> 2, ch = idx & 3;
    bf16x8 kv = {}, vvv = {};
    if (token < NTOK) {
      kv  = *(const bf16x8*)(Kg + (size_t)tokOff[token] + hb + ch * 8);
      vvv = *(const bf16x8*)(Vg + (size_t)tokOff[token] + hb + ch * 8);
    }
    *(bf16x8*)&Ks[token * 40 + ch * 8] = kv;
#pragma unroll
    for (int e = 0; e < 8; ++e)
      Vt[(ch * 8 + e) * 200 + token] = vvv[e];
  }
  __syncthreads();

  // QK^T: wave wv owns q-rows 16*wv..16*wv+15; 12 N-frags cover 192 keys
  f32x4 s[12];
  {
    bf16x8 aq = *(const bf16x8*)&Qs[(wv * 16 + lc) * 40 + lg * 8];
#pragma unroll
    for (int nf = 0; nf < 12; ++nf) {
      bf16x8 bk = *(const bf16x8*)&Ks[(nf * 16 + lc) * 40 + lg * 8];
      f32x4 z = {};
      s[nf] = __builtin_amdgcn_mfma_f32_16x16x32_bf16(aq, bk, z, 0, 0, 0);
    }
  }

  // scale + bias, then row softmax (rows live in 16-lane groups)
  float p[12][4];
  float mx[4] = {-60.f, -60.f, -60.f, -60.f};
#pragma unroll
  for (int nf = 0; nf < 12; ++nf) {
    int kcol = nf * 16 + lc;
#pragma unroll
    for (int r = 0; r < 4; ++r) {
      int q = wv * 16 + lg * 4 + r;
      float val = -60.f;
      if (kcol < NTOK && q < WS2) {
        float bvs;
        if (kcol < WS2) {
          int iq = q / 7, jq = q - iq * 7, ik = kcol / 7, jk = kcol - ik * 7;
          bvs = rpbT[((iq - ik + 6) * 13 + (jq - jk + 6)) * NHEAD + h];
        } else {
          bvs = rpbN[(h * WS2 + q) * NKEY + (kcol - WS2)];
        }
        val = s[nf][r] * SCALE + bvs;
        if (!(val >= -60.f)) val = -60.f;      // also catches NaN
        else if (val > 60.f) val = 60.f;
      }
      p[nf][r] = val;
      mx[r] = fmaxf(mx[r], val);
    }
  }
#pragma unroll
  for (int d = 1; d < 16; d <<= 1)
#pragma unroll
    for (int r = 0; r < 4; ++r) mx[r] = fmaxf(mx[r], __shfl_xor(mx[r], d));

  float sm[4] = {0.f, 0.f, 0.f, 0.f};
#pragma unroll
  for (int nf = 0; nf < 12; ++nf)
#pragma unroll
    for (int r = 0; r < 4; ++r) { p[nf][r] = __expf(p[nf][r] - mx[r]); sm[r] += p[nf][r]; }
#pragma unroll
  for (int d = 1; d < 16; d <<= 1)
#pragma unroll
    for (int r = 0; r < 4; ++r) sm[r] += __shfl_xor(sm[r], d);

  float inv[4];
#pragma unroll
  for (int r = 0; r < 4; ++r) inv[r] = 1.0f / sm[r];

#pragma unroll
  for (int nf = 0; nf < 12; ++nf)
#pragma unroll
    for (int r = 0; r < 4; ++r)
      Ps[(wv * 16 + lg * 4 + r) * 200 + nf * 16 + lc] = (__bf16)(p[nf][r] * inv[r]);
  __syncthreads();

  // PV: out[q][d] = sum_k P[q][k] * V[k][d]; K=192 in 6 steps, 2 N-frags
  f32x4 o[2] = {{}, {}};
#pragma unroll
  for (int ks = 0; ks < 6; ++ks) {
    bf16x8 ap = *(const bf16x8*)&Ps[(wv * 16 + lc) * 200 + ks * 32 + lg * 8];
#pragma unroll
    for (int nf = 0; nf < 2; ++nf) {
      bf16x8 bv = *(const bf16x8*)&Vt[(nf * 16 + lc) * 200 + ks * 32 + lg * 8];
      o[nf] = __builtin_amdgcn_mfma_f32_16x16x32_bf16(ap, bv, o[nf], 0, 0, 0);
    }
  }

#pragma unroll
  for (int nf = 0; nf < 2; ++nf)
#pragma unroll
    for (int r = 0; r < 4; ++r) {
      int q = wv * 16 + lg * 4 + r;
      if (q < WS2)
        Og[(size_t)(win * WS2 + q) * DIM + hb + nf * 16 + lc] = (__bf16)(o[nf][r]);
    }
}

extern "C" void kernel_launch(void* const* d_in, const int* in_sizes, int n_in,
                              void* d_out, int out_size, void* d_ws, size_t ws_size,
                              hipStream_t stream) {
  // ALL inputs are float32 per the reference (jnp.float32); output is float32.
  const float* x      = (const float*)d_in[0];
  const float* w_qkv  = (const float*)d_in[1];
  const float* b_qkv  = (const float*)d_in[2];
  const float* w_proj = (const float*)d_in[3];
  const float* b_proj = (const float*)d_in[4];
  const float* rpbT   = (const float*)d_in[5];
  const float* rpbN   = (const float*)d_in[6];
  // d_in[7], d_in[8] = H, W scalars (168, fixed by setup_inputs) — hardcoded.

  float* out = (float*)d_out;
  const size_t planeElems = (size_t)MTOT * DIM;  // 21,676,032 == out_size

  // Workspace plan:
  //   d_out (86.7 MB f32) temporarily holds TWO bf16 planes: K then V
  //     (both fully consumed by attn before gemm3 overwrites d_out).
  //   d_ws holds the window-ordered Q/O bf16 plane (43.4 MB).
  __bf16* k_ws  = (__bf16*)d_out;
  __bf16* v_ws  = k_ws + planeElems;
  __bf16* qo_ws = (__bf16*)d_ws;

  // 1) QKV projection: (56448 x 384) @ (1152 x 384)^T -> q (window-ordered), k, v
  gemm_bt<float, __bf16><<<dim3(1152 / 128, MTOT / 128), 256, 0, stream>>>(
      x, w_qkv, b_qkv, qo_ws, k_ws, v_ws, DIM, DIM, 1);

  // 2) windowed attention with rolled-neighbor keys (O overwrites Q plane)
  attn_win<<<dim3(NWIN, NHEAD), 256, 0, stream>>>(qo_ws, k_ws, v_ws, rpbT, rpbN, qo_ws);

  // 3) output projection: (56448 x 384) @ (384 x 384)^T -> f32 out
  gemm_bt<__bf16, float><<<dim3(384 / 128, MTOT / 128), 256, 0, stream>>>(
      qo_ws, w_proj, b_proj, out, out, out, DIM, DIM, 0);
}

// Round 4
// 399.896 us; speedup vs baseline: 1.5025x; 1.5025x over previous
//
#include <hip/hip_runtime.h>
#include <hip/hip_bf16.h>
#include <stdint.h>

typedef __attribute__((ext_vector_type(8))) __bf16 bf16x8;
typedef __attribute__((ext_vector_type(4))) float f32x4;

#define DEVINL static __device__ __forceinline__

constexpr int WSZ = 7, EXPAND = 3, NHEAD = 12, DIM = 384, HDIM = 32;
constexpr int WS2 = 49, NKEY = 132, NTOK = 181;
constexpr int BB = 2, HH = 168, WW = 168;
constexpr int NWY = HH / WSZ, NWX = WW / WSZ;        // 24, 24
constexpr int NWIN = BB * NWY * NWX;                 // 1152
constexpr int MTOT = BB * HH * WW;                   // 56448
constexpr float SCALE = 0.1767766952966369f;         // 32^-0.5

// ---- neighbor offset table (replicates _valid_ind_rolled order) ----
struct NbrTab { int dy[NKEY]; int dx[NKEY]; };
constexpr NbrTab make_nbr() {
  NbrTab t{};
  int n = 0;
  for (int quad = 0; quad < 4; ++quad)
    for (int i = 0; i < WSZ; ++i)
      for (int j = 0; j < WSZ; ++j) {
        bool drop;
        if (quad == 0)      drop = (i < WSZ - EXPAND) && (j < WSZ - EXPAND);
        else if (quad == 1) drop = (i < WSZ - EXPAND) && (j >= EXPAND);
        else if (quad == 2) drop = (i >= EXPAND)      && (j < WSZ - EXPAND);
        else                drop = (i >= EXPAND)      && (j >= EXPAND);
        if (!drop) {
          t.dy[n] = (quad < 2)        ? i + EXPAND : i - EXPAND;
          t.dx[n] = ((quad & 1) == 0) ? j + EXPAND : j - EXPAND;
          ++n;
        }
      }
  return t;
}
__device__ constexpr NbrTab NTAB = make_nbr();

// bijective XCD-chunked swizzle: consecutive L land in the same XCD chunk
DEVINL int xcd_swizzle(int bid, int nwg) {
  int q8 = nwg >> 3, r8 = nwg & 7;
  int xcd = bid & 7, ii = bid >> 3;
  return (xcd < r8 ? xcd * (q8 + 1) : r8 * (q8 + 1) + (xcd - r8) * q8) + ii;
}

// pixel-row -> window-ordered row permutation
DEVINL int qperm(int m) {
  int b = m / (HH * WW);
  int rem = m - b * (HH * WW);
  int y = rem / WW;
  int x = rem - y * WW;
  int win = b * (NWY * NWX) + (y / WSZ) * NWX + (x / WSZ);
  int qi = (y % WSZ) * WSZ + (x % WSZ);
  return win * WS2 + qi;
}

DEVINL bf16x8 load8_cvt(const float* p) {
  float4 a = *(const float4*)p;
  float4 b = *(const float4*)(p + 4);
  bf16x8 r = {(__bf16)a.x, (__bf16)a.y, (__bf16)a.z, (__bf16)a.w,
              (__bf16)b.x, (__bf16)b.y, (__bf16)b.z, (__bf16)b.w};
  return r;
}
DEVINL bf16x8 load8_cvt(const __bf16* p) { return *(const bf16x8*)p; }

// ---- GEMM: out[m][n] = sum_k A[m][k] * Bt[n][k] + bias[n] ----
// 1-D grid, XCD-chunked swizzle (n-tiles of one m-slab stay in one XCD's L2).
template <typename AT, typename OT>
__global__ __launch_bounds__(256) void gemm_bt(
    const AT* __restrict__ A, const float* __restrict__ Bt,
    const float* __restrict__ bias,
    OT* __restrict__ O0, OT* __restrict__ O1, OT* __restrict__ O2,
    int K, int NoutPer, int qPerm, int nxt) {
  __shared__ __bf16 As[128 * 64];
  __shared__ __bf16 Bs[128 * 64];

  const int t = threadIdx.x;
  const int wv = t >> 6, ln = t & 63;
  const int lc = ln & 15, kg = (ln >> 4) * 8;
  const int wm = wv >> 1, wn = wv & 1;
  const int L = xcd_swizzle(blockIdx.x, gridDim.x);
  const int mt = L / nxt, nt = L - mt * nxt;
  const int m0 = mt * 128, n0 = nt * 128;
  const int srow = t >> 3, scol = (t & 7) * 8;

  f32x4 acc[4][4] = {};

  for (int kt = 0; kt < K; kt += 64) {
#pragma unroll
    for (int i = 0; i < 4; ++i) {
      int row = i * 32 + srow;
      bf16x8 av = load8_cvt(A + (size_t)(m0 + row) * K + kt + scol);
      *(bf16x8*)&As[row * 64 + scol] = av;
      bf16x8 bv = load8_cvt(Bt + (size_t)(n0 + row) * K + kt + scol);
      *(bf16x8*)&Bs[row * 64 + scol] = bv;
    }
    __syncthreads();
#pragma unroll
    for (int ks = 0; ks < 2; ++ks) {
      bf16x8 af[4], bb[4];
#pragma unroll
      for (int m = 0; m < 4; ++m)
        af[m] = *(const bf16x8*)&As[(wm * 64 + m * 16 + lc) * 64 + ks * 32 + kg];
#pragma unroll
      for (int n = 0; n < 4; ++n)
        bb[n] = *(const bf16x8*)&Bs[(wn * 64 + n * 16 + lc) * 64 + ks * 32 + kg];
#pragma unroll
      for (int m = 0; m < 4; ++m)
#pragma unroll
        for (int n = 0; n < 4; ++n)
          acc[m][n] = __builtin_amdgcn_mfma_f32_16x16x32_bf16(af[m], bb[n], acc[m][n], 0, 0, 0);
    }
    __syncthreads();
  }

  OT* outs[3] = {O0, O1, O2};
#pragma unroll
  for (int n = 0; n < 4; ++n) {
    int col = n0 + wn * 64 + n * 16 + lc;
    int sel = col / NoutPer;
    int c = col - sel * NoutPer;
    float bv = bias[col];
    OT* op = outs[sel];
    bool perm = qPerm && (sel == 0);
#pragma unroll
    for (int m = 0; m < 4; ++m) {
      int row = m0 + wm * 64 + m * 16 + (ln >> 4) * 4;
#pragma unroll
      for (int r = 0; r < 4; ++r) {
        int rr = row + r;
        int orow = perm ? qperm(rr) : rr;
        op[(size_t)orow * NoutPer + c] = (OT)(acc[m][n][r] + bv);
      }
    }
  }
}

// ---- attention: one block per (window, head), 4 waves, 38.4 KB LDS ----
// Qg window-ordered (rows win*49+q), read DIRECTLY from global (L2-hot).
// Kg/Vg pixel-ordered bf16 planes. Og aliases Qg (disjoint head columns).
// LDS: region0 (12800 elems) = Ks[192][40] during QK^T, then Ps[64][200];
//      Vt[32][200] after it.
__global__ __launch_bounds__(256) void attn_win(
    const __bf16* __restrict__ Qg, const __bf16* __restrict__ Kg, const __bf16* __restrict__ Vg,
    const float* __restrict__ rpbT, const float* __restrict__ rpbN,
    __bf16* __restrict__ Og) {
  __shared__ __bf16 smem[12800 + 32 * 200];
  __bf16* Ks = smem;           // [192][40]
  __bf16* Ps = smem;           // [64][200], aliases Ks after QK^T
  __bf16* Vt = smem + 12800;   // [32][200]

  const int L = xcd_swizzle(blockIdx.x, NWIN * NHEAD);  // nwg = 13824, r=0
  const int win = L / NHEAD, h = L - win * NHEAD;
  const int b = win / (NWY * NWX);
  const int wrem = win - b * (NWY * NWX);
  const int wy = wrem / NWX, wx = wrem - wy * NWX;
  const int y0 = wy * WSZ, x0 = wx * WSZ;

  const int t = threadIdx.x;
  const int wv = t >> 6, ln = t & 63;
  const int lc = ln & 15, lg = ln >> 4;
  const int hb = h * HDIM;

  // Q fragment straight from global (issues early, overlaps staging)
  bf16x8 aq = {};
  {
    int qrow = wv * 16 + lc;
    if (qrow < WS2)
      aq = *(const bf16x8*)(Qg + (size_t)(win * WS2 + qrow) * DIM + hb + lg * 8);
  }

  // stage K (row-major, stride 40) and V^T (stride 200): 192 tokens x 4 chunks
#pragma unroll
  for (int it = 0; it < 3; ++it) {
    int idx = t + it * 256;
    int token = idx >> 2, ch = idx & 3;
    bool valid = token < NTOK;
    size_t off = 0;
    if (token < WS2) {
      int yy = y0 + token / WSZ, xx = x0 + token % WSZ;
      off = (size_t)(((b * HH + yy) * WW + xx)) * DIM;
    } else if (valid) {
      int j = token - WS2;
      int yy = y0 + NTAB.dy[j], xx = x0 + NTAB.dx[j];
      if (yy < 0) yy += HH; else if (yy >= HH) yy -= HH;
      if (xx < 0) xx += WW; else if (xx >= WW) xx -= WW;
      off = (size_t)(((b * HH + yy) * WW + xx)) * DIM;
    }
    bf16x8 kv = {}, vv = {};
    if (valid) {
      kv = *(const bf16x8*)(Kg + off + hb + ch * 8);
      vv = *(const bf16x8*)(Vg + off + hb + ch * 8);
    }
    *(bf16x8*)&Ks[token * 40 + ch * 8] = kv;
#pragma unroll
    for (int e = 0; e < 8; ++e)
      Vt[(ch * 8 + e) * 200 + token] = vv[e];
  }
  __syncthreads();

  // QK^T: wave wv owns q-rows 16*wv..16*wv+15; 12 N-frags cover 192 keys
  f32x4 s[12];
#pragma unroll
  for (int nf = 0; nf < 12; ++nf) {
    bf16x8 bk = *(const bf16x8*)&Ks[(nf * 16 + lc) * 40 + lg * 8];
    f32x4 z = {};
    s[nf] = __builtin_amdgcn_mfma_f32_16x16x32_bf16(aq, bk, z, 0, 0, 0);
  }
  __syncthreads();  // Ks reads complete before Ps overwrites the region

  // scale + bias, then row softmax (rows live in 16-lane groups)
  float p[12][4];
  float mx[4] = {-60.f, -60.f, -60.f, -60.f};
#pragma unroll
  for (int nf = 0; nf < 12; ++nf) {
    int kcol = nf * 16 + lc;
#pragma unroll
    for (int r = 0; r < 4; ++r) {
      int q = wv * 16 + lg * 4 + r;
      float val = -60.f;
      if (kcol < NTOK && q < WS2) {
        float bvs;
        if (kcol < WS2) {
          int iq = q / 7, jq = q - iq * 7, ik = kcol / 7, jk = kcol - ik * 7;
          bvs = rpbT[((iq - ik + 6) * 13 + (jq - jk + 6)) * NHEAD + h];
        } else {
          bvs = rpbN[(h * WS2 + q) * NKEY + (kcol - WS2)];
        }
        val = s[nf][r] * SCALE + bvs;
        if (!(val >= -60.f)) val = -60.f;      // also catches NaN
        else if (val > 60.f) val = 60.f;
      }
      p[nf][r] = val;
      mx[r] = fmaxf(mx[r], val);
    }
  }
#pragma unroll
  for (int d = 1; d < 16; d <<= 1)
#pragma unroll
    for (int r = 0; r < 4; ++r) mx[r] = fmaxf(mx[r], __shfl_xor(mx[r], d));

  float sm[4] = {0.f, 0.f, 0.f, 0.f};
#pragma unroll
  for (int nf = 0; nf < 12; ++nf)
#pragma unroll
    for (int r = 0; r < 4; ++r) { p[nf][r] = __expf(p[nf][r] - mx[r]); sm[r] += p[nf][r]; }
#pragma unroll
  for (int d = 1; d < 16; d <<= 1)
#pragma unroll
    for (int r = 0; r < 4; ++r) sm[r] += __shfl_xor(sm[r], d);

  float inv[4];
#pragma unroll
  for (int r = 0; r < 4; ++r) inv[r] = 1.0f / sm[r];

#pragma unroll
  for (int nf = 0; nf < 12; ++nf)
#pragma unroll
    for (int r = 0; r < 4; ++r)
      Ps[(wv * 16 + lg * 4 + r) * 200 + nf * 16 + lc] = (__bf16)(p[nf][r] * inv[r]);
  __syncthreads();

  // PV: out[q][d] = sum_k P[q][k] * V[k][d]; K=192 in 6 steps, 2 N-frags
  f32x4 o[2] = {{}, {}};
#pragma unroll
  for (int ks = 0; ks < 6; ++ks) {
    bf16x8 ap = *(const bf16x8*)&Ps[(wv * 16 + lc) * 200 + ks * 32 + lg * 8];
#pragma unroll
    for (int nf = 0; nf < 2; ++nf) {
      bf16x8 bv = *(const bf16x8*)&Vt[(nf * 16 + lc) * 200 + ks * 32 + lg * 8];
      o[nf] = __builtin_amdgcn_mfma_f32_16x16x32_bf16(ap, bv, o[nf], 0, 0, 0);
    }
  }

#pragma unroll
  for (int nf = 0; nf < 2; ++nf)
#pragma unroll
    for (int r = 0; r < 4; ++r) {
      int q = wv * 16 + lg * 4 + r;
      if (q < WS2)
        Og[(size_t)(win * WS2 + q) * DIM + hb + nf * 16 + lc] = (__bf16)(o[nf][r]);
    }
}

extern "C" void kernel_launch(void* const* d_in, const int* in_sizes, int n_in,
                              void* d_out, int out_size, void* d_ws, size_t ws_size,
                              hipStream_t stream) {
  const float* x      = (const float*)d_in[0];
  const float* w_qkv  = (const float*)d_in[1];
  const float* b_qkv  = (const float*)d_in[2];
  const float* w_proj = (const float*)d_in[3];
  const float* b_proj = (const float*)d_in[4];
  const float* rpbT   = (const float*)d_in[5];
  const float* rpbN   = (const float*)d_in[6];

  float* out = (float*)d_out;
  const size_t planeElems = (size_t)MTOT * DIM;  // 21,676,032 == out_size

  // d_out (86.7 MB f32) temporarily holds the K and V bf16 planes (dead before
  // gemm3 overwrites). d_ws holds the window-ordered Q/O bf16 plane (43.4 MB).
  __bf16* k_ws  = (__bf16*)d_out;
  __bf16* v_ws  = k_ws + planeElems;
  __bf16* qo_ws = (__bf16*)d_ws;

  // 1) QKV projection -> q (window-ordered), k, v
  gemm_bt<float, __bf16><<<dim3((1152 / 128) * (MTOT / 128)), 256, 0, stream>>>(
      x, w_qkv, b_qkv, qo_ws, k_ws, v_ws, DIM, DIM, 1, 1152 / 128);

  // 2) windowed attention with rolled-neighbor keys (O overwrites Q plane)
  attn_win<<<dim3(NWIN * NHEAD), 256, 0, stream>>>(qo_ws, k_ws, v_ws, rpbT, rpbN, qo_ws);

  // 3) output projection -> f32 out
  gemm_bt<__bf16, float><<<dim3((384 / 128) * (MTOT / 128)), 256, 0, stream>>>(
      qo_ws, w_proj, b_proj, out, out, out, DIM, DIM, 0, 384 / 128);
}

// Round 5
// 375.128 us; speedup vs baseline: 1.6017x; 1.0660x over previous
//
#include <hip/hip_runtime.h>
#include <hip/hip_bf16.h>
#include <stdint.h>

typedef __attribute__((ext_vector_type(8))) __bf16 bf16x8;
typedef __attribute__((ext_vector_type(4))) float f32x4;

#define DEVINL static __device__ __forceinline__

constexpr int WSZ = 7, EXPAND = 3, NHEAD = 12, DIM = 384, HDIM = 32;
constexpr int WS2 = 49, NKEY = 132, NTOK = 181;
constexpr int BB = 2, HH = 168, WW = 168;
constexpr int NWY = HH / WSZ, NWX = WW / WSZ;        // 24, 24
constexpr int NWIN = BB * NWY * NWX;                 // 1152
constexpr int MTOT = BB * HH * WW;                   // 56448
constexpr float SCALE = 0.1767766952966369f;         // 32^-0.5

// ---- packed token offset table: (dy+8)<<5 | (dx+8), window-relative ----
// tokens 0..48: in-window; 49..180: rolled neighbors (_valid_ind_rolled order);
// 181..191: padding (center, loads skipped).
struct TokTab { int v[192]; };
constexpr TokTab make_toktab() {
  TokTab tt{};
  for (int t = 0; t < 192; ++t) tt.v[t] = 8 * 32 + 8;
  for (int t = 0; t < WS2; ++t) tt.v[t] = (t / WSZ + 8) * 32 + (t % WSZ + 8);
  int n = WS2;
  for (int quad = 0; quad < 4; ++quad)
    for (int i = 0; i < WSZ; ++i)
      for (int j = 0; j < WSZ; ++j) {
        bool drop;
        if (quad == 0)      drop = (i < WSZ - EXPAND) && (j < WSZ - EXPAND);
        else if (quad == 1) drop = (i < WSZ - EXPAND) && (j >= EXPAND);
        else if (quad == 2) drop = (i >= EXPAND)      && (j < WSZ - EXPAND);
        else                drop = (i >= EXPAND)      && (j >= EXPAND);
        if (!drop) {
          int dy = (quad < 2)        ? i + EXPAND : i - EXPAND;
          int dx = ((quad & 1) == 0) ? j + EXPAND : j - EXPAND;
          tt.v[n++] = (dy + 8) * 32 + (dx + 8);
        }
      }
  return tt;
}
__device__ constexpr TokTab TOKTAB = make_toktab();

// bijective XCD-chunked swizzle: consecutive L land in the same XCD chunk
DEVINL int xcd_swizzle(int bid, int nwg) {
  int q8 = nwg >> 3, r8 = nwg & 7;
  int xcd = bid & 7, ii = bid >> 3;
  return (xcd < r8 ? xcd * (q8 + 1) : r8 * (q8 + 1) + (xcd - r8) * q8) + ii;
}

// pixel-row -> window-ordered row permutation
DEVINL int qperm(int m) {
  int b = m / (HH * WW);
  int rem = m - b * (HH * WW);
  int y = rem / WW;
  int x = rem - y * WW;
  int win = b * (NWY * NWX) + (y / WSZ) * NWX + (x / WSZ);
  int qi = (y % WSZ) * WSZ + (x % WSZ);
  return win * WS2 + qi;
}

DEVINL bf16x8 load8_cvt(const float* p) {
  float4 a = *(const float4*)p;
  float4 b = *(const float4*)(p + 4);
  bf16x8 r = {(__bf16)a.x, (__bf16)a.y, (__bf16)a.z, (__bf16)a.w,
              (__bf16)b.x, (__bf16)b.y, (__bf16)b.z, (__bf16)b.w};
  return r;
}
DEVINL bf16x8 load8_cvt(const __bf16* p) { return *(const bf16x8*)p; }

// ---- GEMM: out[m][n] = sum_k A[m][k] * Bt[n][k] + bias[n] ----
// 1-D grid, XCD-chunked swizzle (n-tiles of one m-slab stay in one XCD's L2).
template <typename AT, typename OT>
__global__ __launch_bounds__(256) void gemm_bt(
    const AT* __restrict__ A, const float* __restrict__ Bt,
    const float* __restrict__ bias,
    OT* __restrict__ O0, OT* __restrict__ O1, OT* __restrict__ O2,
    int K, int NoutPer, int qPerm, int nxt) {
  __shared__ __bf16 As[128 * 64];
  __shared__ __bf16 Bs[128 * 64];

  const int t = threadIdx.x;
  const int wv = t >> 6, ln = t & 63;
  const int lc = ln & 15, kg = (ln >> 4) * 8;
  const int wm = wv >> 1, wn = wv & 1;
  const int L = xcd_swizzle(blockIdx.x, gridDim.x);
  const int mt = L / nxt, nt = L - mt * nxt;
  const int m0 = mt * 128, n0 = nt * 128;
  const int srow = t >> 3, scol = (t & 7) * 8;

  f32x4 acc[4][4] = {};

  for (int kt = 0; kt < K; kt += 64) {
#pragma unroll
    for (int i = 0; i < 4; ++i) {
      int row = i * 32 + srow;
      bf16x8 av = load8_cvt(A + (size_t)(m0 + row) * K + kt + scol);
      *(bf16x8*)&As[row * 64 + scol] = av;
      bf16x8 bv = load8_cvt(Bt + (size_t)(n0 + row) * K + kt + scol);
      *(bf16x8*)&Bs[row * 64 + scol] = bv;
    }
    __syncthreads();
#pragma unroll
    for (int ks = 0; ks < 2; ++ks) {
      bf16x8 af[4], bb[4];
#pragma unroll
      for (int m = 0; m < 4; ++m)
        af[m] = *(const bf16x8*)&As[(wm * 64 + m * 16 + lc) * 64 + ks * 32 + kg];
#pragma unroll
      for (int n = 0; n < 4; ++n)
        bb[n] = *(const bf16x8*)&Bs[(wn * 64 + n * 16 + lc) * 64 + ks * 32 + kg];
#pragma unroll
      for (int m = 0; m < 4; ++m)
#pragma unroll
        for (int n = 0; n < 4; ++n)
          acc[m][n] = __builtin_amdgcn_mfma_f32_16x16x32_bf16(af[m], bb[n], acc[m][n], 0, 0, 0);
    }
    __syncthreads();
  }

  OT* outs[3] = {O0, O1, O2};
#pragma unroll
  for (int n = 0; n < 4; ++n) {
    int col = n0 + wn * 64 + n * 16 + lc;
    int sel = col / NoutPer;
    int c = col - sel * NoutPer;
    float bv = bias[col];
    OT* op = outs[sel];
    bool perm = qPerm && (sel == 0);
#pragma unroll
    for (int m = 0; m < 4; ++m) {
      int row = m0 + wm * 64 + m * 16 + (ln >> 4) * 4;
#pragma unroll
      for (int r = 0; r < 4; ++r) {
        int rr = row + r;
        int orow = perm ? qperm(rr) : rr;
        op[(size_t)orow * NoutPer + c] = (OT)(acc[m][n][r] + bv);
      }
    }
  }
}

// ---- attention: one block per (window, head), 4 waves, 32.4 KB LDS ----
// Qg window-ordered, read directly from global (L2-hot). Og aliases Qg.
// LDS: region0 (9800 elems) = Ks[192][40] during QK^T, then Ps[49][200]
//      (rotate-swizzled); Vt[32][200] (rotate-swizzled) after it.
__global__ __launch_bounds__(256, 5) void attn_win(
    const __bf16* __restrict__ Qg, const __bf16* __restrict__ Kg, const __bf16* __restrict__ Vg,
    const float* __restrict__ rpbT, const float* __restrict__ rpbN,
    __bf16* __restrict__ Og) {
  __shared__ __bf16 smem[9800 + 32 * 200];
  __bf16* Ks = smem;           // [192][40]
  __bf16* Ps = smem;           // [49][200] rotated, aliases Ks after QK^T
  __bf16* Vt = smem + 9800;    // [32][200] rotated: col = (token + (d>>3)*16) % 200

  const int L = xcd_swizzle(blockIdx.x, NWIN * NHEAD);
  const int win = L / NHEAD, h = L - win * NHEAD;
  const int b = win / (NWY * NWX);
  const int wrem = win - b * (NWY * NWX);
  const int wy = wrem / NWX, wx = wrem - wy * NWX;
  const int y0 = wy * WSZ, x0 = wx * WSZ;

  const int t = threadIdx.x;
  const int wv = t >> 6, ln = t & 63;
  const int lc = ln & 15, lg = ln >> 4;
  const int hb = h * HDIM;

  // Q fragment straight from global (issues early, overlaps staging)
  bf16x8 aq = {};
  {
    int qrow = wv * 16 + lc;
    if (qrow < WS2)
      aq = *(const bf16x8*)(Qg + (size_t)(win * WS2 + qrow) * DIM + hb + lg * 8);
  }

  // stage K (row-major, stride 40) and V^T (rotated): 192 tokens x 4 chunks
#pragma unroll
  for (int it = 0; it < 3; ++it) {
    int idx = t + it * 256;
    int token = idx >> 2, ch = idx & 3;
    int pk = TOKTAB.v[token];
    int yy = y0 + (pk >> 5) - 8;
    int xx = x0 + (pk & 31) - 8;
    if (yy < 0) yy += HH; else if (yy >= HH) yy -= HH;
    if (xx < 0) xx += WW; else if (xx >= WW) xx -= WW;
    size_t off = (size_t)((b * HH + yy) * WW + xx) * DIM + hb + ch * 8;
    bf16x8 kv = {}, vv = {};
    if (token < NTOK) {
      kv = *(const bf16x8*)(Kg + off);
      vv = *(const bf16x8*)(Vg + off);
    }
    *(bf16x8*)&Ks[token * 40 + ch * 8] = kv;
    int col2 = token + ch * 16; if (col2 >= 200) col2 -= 200;
#pragma unroll
    for (int e = 0; e < 8; ++e)
      Vt[(ch * 8 + e) * 200 + col2] = vv[e];
  }
  __syncthreads();

  // QK^T: wave wv owns q-rows 16*wv..16*wv+15; 12 N-frags cover 192 keys
  f32x4 s[12];
#pragma unroll
  for (int nf = 0; nf < 12; ++nf) {
    bf16x8 bk = *(const bf16x8*)&Ks[(nf * 16 + lc) * 40 + lg * 8];
    f32x4 z = {};
    s[nf] = __builtin_amdgcn_mfma_f32_16x16x32_bf16(aq, bk, z, 0, 0, 0);
  }
  __syncthreads();  // Ks reads complete before Ps overwrites the region

  // scale + bias (+ additive mask for pad cols), then row softmax
  float p[12][4];
  float mx[4] = {-60.f, -60.f, -60.f, -60.f};
#pragma unroll
  for (int nf = 0; nf < 12; ++nf) {
    int kcol = nf * 16 + lc;
    int kc = min(kcol, NTOK - 1);
    float kmask = (kcol < NTOK) ? 0.f : -60.f;
    int ik = kc / 7, jk = kc - ik * 7;
#pragma unroll
    for (int r = 0; r < 4; ++r) {
      int q = wv * 16 + lg * 4 + r;
      int qc = min(q, WS2 - 1);
      float bvs;
      if (kcol < WS2) {
        int iq = qc / 7, jq = qc - iq * 7;
        bvs = rpbT[((iq - ik + 6) * 13 + (jq - jk + 6)) * NHEAD + h];
      } else {
        bvs = rpbN[(h * WS2 + qc) * NKEY + (kc - WS2)];
      }
      float val = s[nf][r] * SCALE + bvs + kmask;
      p[nf][r] = val;
      mx[r] = fmaxf(mx[r], val);
    }
  }
#pragma unroll
  for (int d = 1; d < 16; d <<= 1)
#pragma unroll
    for (int r = 0; r < 4; ++r) mx[r] = fmaxf(mx[r], __shfl_xor(mx[r], d));

  float sm[4] = {0.f, 0.f, 0.f, 0.f};
#pragma unroll
  for (int nf = 0; nf < 12; ++nf)
#pragma unroll
    for (int r = 0; r < 4; ++r) { p[nf][r] = __expf(p[nf][r] - mx[r]); sm[r] += p[nf][r]; }
#pragma unroll
  for (int d = 1; d < 16; d <<= 1)
#pragma unroll
    for (int r = 0; r < 4; ++r) sm[r] += __shfl_xor(sm[r], d);

  float inv[4];
#pragma unroll
  for (int r = 0; r < 4; ++r) inv[r] = 1.0f / sm[r];

  // Ps write (rotated, rows < 49 only)
#pragma unroll
  for (int nf = 0; nf < 12; ++nf) {
    int kcol = nf * 16 + lc;
#pragma unroll
    for (int r = 0; r < 4; ++r) {
      int q = wv * 16 + lg * 4 + r;
      if (q < WS2) {
        int c2 = kcol + ((q >> 3) & 1) * 16; if (c2 >= 200) c2 -= 200;
        Ps[q * 200 + c2] = (__bf16)(p[nf][r] * inv[r]);
      }
    }
  }
  __syncthreads();

  // PV: out[q][d] = sum_k P[q][k] * V[k][d]; K=192 in 6 steps, 2 N-frags
  f32x4 o[2] = {{}, {}};
  const int rowP = wv * 16 + lc;
  const int rotP = ((lc >> 3) & 1) * 16;
#pragma unroll
  for (int ks = 0; ks < 6; ++ks) {
    int c0 = ks * 32 + lg * 8 + rotP; if (c0 >= 200) c0 -= 200;
    bf16x8 ap = *(const bf16x8*)&Ps[rowP * 200 + c0];
#pragma unroll
    for (int nf = 0; nf < 2; ++nf) {
      int rowV = nf * 16 + lc;
      int cv = ks * 32 + lg * 8 + (rowV >> 3) * 16; if (cv >= 200) cv -= 200;
      bf16x8 bv = *(const bf16x8*)&Vt[rowV * 200 + cv];
      o[nf] = __builtin_amdgcn_mfma_f32_16x16x32_bf16(ap, bv, o[nf], 0, 0, 0);
    }
  }

#pragma unroll
  for (int nf = 0; nf < 2; ++nf)
#pragma unroll
    for (int r = 0; r < 4; ++r) {
      int q = wv * 16 + lg * 4 + r;
      if (q < WS2)
        Og[(size_t)(win * WS2 + q) * DIM + hb + nf * 16 + lc] = (__bf16)(o[nf][r]);
    }
}

extern "C" void kernel_launch(void* const* d_in, const int* in_sizes, int n_in,
                              void* d_out, int out_size, void* d_ws, size_t ws_size,
                              hipStream_t stream) {
  const float* x      = (const float*)d_in[0];
  const float* w_qkv  = (const float*)d_in[1];
  const float* b_qkv  = (const float*)d_in[2];
  const float* w_proj = (const float*)d_in[3];
  const float* b_proj = (const float*)d_in[4];
  const float* rpbT   = (const float*)d_in[5];
  const float* rpbN   = (const float*)d_in[6];

  float* out = (float*)d_out;
  const size_t planeElems = (size_t)MTOT * DIM;  // 21,676,032 == out_size

  // d_out (86.7 MB f32) temporarily holds the K and V bf16 planes (dead before
  // gemm3 overwrites). d_ws holds the window-ordered Q/O bf16 plane (43.4 MB).
  __bf16* k_ws  = (__bf16*)d_out;
  __bf16* v_ws  = k_ws + planeElems;
  __bf16* qo_ws = (__bf16*)d_ws;

  // 1) QKV projection -> q (window-ordered), k, v
  gemm_bt<float, __bf16><<<dim3((1152 / 128) * (MTOT / 128)), 256, 0, stream>>>(
      x, w_qkv, b_qkv, qo_ws, k_ws, v_ws, DIM, DIM, 1, 1152 / 128);

  // 2) windowed attention with rolled-neighbor keys (O overwrites Q plane)
  attn_win<<<dim3(NWIN * NHEAD), 256, 0, stream>>>(qo_ws, k_ws, v_ws, rpbT, rpbN, qo_ws);

  // 3) output projection -> f32 out
  gemm_bt<__bf16, float><<<dim3((384 / 128) * (MTOT / 128)), 256, 0, stream>>>(
      qo_ws, w_proj, b_proj, out, out, out, DIM, DIM, 0, 384 / 128);
}

// Round 6
// 334.915 us; speedup vs baseline: 1.7940x; 1.1201x over previous
//
#include <hip/hip_runtime.h>
#include <hip/hip_bf16.h>
#include <stdint.h>

typedef __attribute__((ext_vector_type(8))) __bf16 bf16x8;
typedef __attribute__((ext_vector_type(4))) float f32x4;

#define DEVINL static __device__ __forceinline__

constexpr int WSZ = 7, EXPAND = 3, NHEAD = 12, DIM = 384, HDIM = 32;
constexpr int WS2 = 49, NKEY = 132, NTOK = 181;
constexpr int BB = 2, HH = 168, WW = 168;
constexpr int NWY = HH / WSZ, NWX = WW / WSZ;        // 24, 24
constexpr int NWIN = BB * NWY * NWX;                 // 1152
constexpr int MTOT = BB * HH * WW;                   // 56448
constexpr float SCALE = 0.1767766952966369f;         // 32^-0.5
constexpr size_t PLANE = (size_t)MTOT * DIM;         // 21,676,032
constexpr int NQKV = 3 * DIM * DIM;                  // 442,368
constexpr int NPROJ = DIM * DIM;                     // 147,456

// ---- packed token offset table: (dy+8)<<5 | (dx+8), window-relative ----
struct TokTab { int v[192]; };
constexpr TokTab make_toktab() {
  TokTab tt{};
  for (int t = 0; t < 192; ++t) tt.v[t] = 8 * 32 + 8;
  for (int t = 0; t < WS2; ++t) tt.v[t] = (t / WSZ + 8) * 32 + (t % WSZ + 8);
  int n = WS2;
  for (int quad = 0; quad < 4; ++quad)
    for (int i = 0; i < WSZ; ++i)
      for (int j = 0; j < WSZ; ++j) {
        bool drop;
        if (quad == 0)      drop = (i < WSZ - EXPAND) && (j < WSZ - EXPAND);
        else if (quad == 1) drop = (i < WSZ - EXPAND) && (j >= EXPAND);
        else if (quad == 2) drop = (i >= EXPAND)      && (j < WSZ - EXPAND);
        else                drop = (i >= EXPAND)      && (j >= EXPAND);
        if (!drop) {
          int dy = (quad < 2)        ? i + EXPAND : i - EXPAND;
          int dx = ((quad & 1) == 0) ? j + EXPAND : j - EXPAND;
          tt.v[n++] = (dy + 8) * 32 + (dx + 8);
        }
      }
  return tt;
}
__device__ constexpr TokTab TOKTAB = make_toktab();

DEVINL int xcd_swizzle(int bid, int nwg) {
  int q8 = nwg >> 3, r8 = nwg & 7;
  int xcd = bid & 7, ii = bid >> 3;
  return (xcd < r8 ? xcd * (q8 + 1) : r8 * (q8 + 1) + (xcd - r8) * q8) + ii;
}

// pixel-row -> window-ordered row permutation (fallback path only)
DEVINL int qperm(int m) {
  int b = m / (HH * WW);
  int rem = m - b * (HH * WW);
  int y = rem / WW;
  int x = rem - y * WW;
  int win = b * (NWY * NWX) + (y / WSZ) * NWX + (x / WSZ);
  int qi = (y % WSZ) * WSZ + (x % WSZ);
  return win * WS2 + qi;
}

DEVINL bf16x8 load8_cvt(const float* p) {
  float4 a = *(const float4*)p;
  float4 b = *(const float4*)(p + 4);
  bf16x8 r = {(__bf16)a.x, (__bf16)a.y, (__bf16)a.z, (__bf16)a.w,
              (__bf16)b.x, (__bf16)b.y, (__bf16)b.z, (__bf16)b.w};
  return r;
}
DEVINL bf16x8 load8_cvt(const __bf16* p) { return *(const bf16x8*)p; }

DEVINL void gload16(const __bf16* g, __bf16* l) {
  __builtin_amdgcn_global_load_lds(
      (const __attribute__((address_space(1))) unsigned int*)g,
      (__attribute__((address_space(3))) unsigned int*)l, 16, 0, 0);
}

// ---- f32 -> bf16 pre-convert: x, w_qkv, w_proj in one launch ----
constexpr int XG8 = PLANE / 8;            // 2,709,504
constexpr int QG8 = NQKV / 8;             // 55,296
constexpr int PG8 = NPROJ / 8;            // 18,432
constexpr int CVT_GRID = (XG8 + QG8 + PG8) / 256;  // 10,872 exact

__global__ __launch_bounds__(256) void cvt3(
    const float* __restrict__ a, const float* __restrict__ b, const float* __restrict__ c,
    __bf16* __restrict__ da, __bf16* __restrict__ db, __bf16* __restrict__ dc) {
  int i = blockIdx.x * 256 + threadIdx.x;
  const float* s; __bf16* d; int j;
  if (i < XG8)            { s = a; d = da; j = i; }
  else if (i < XG8 + QG8) { s = b; d = db; j = i - XG8; }
  else                    { s = c; d = dc; j = i - XG8 - QG8; }
  *(bf16x8*)(d + (size_t)j * 8) = load8_cvt(s + (size_t)j * 8);
}

// ---- fast GEMM (bf16 A and Bt, global_load_lds staging, m97 structure) ----
template <typename OT>
__global__ __launch_bounds__(256) void gemm_fast(
    const __bf16* __restrict__ A, const __bf16* __restrict__ Bt,
    const float* __restrict__ bias,
    OT* __restrict__ O0, OT* __restrict__ O1, OT* __restrict__ O2,
    int K, int NoutPer, int nxt) {
  __shared__ __bf16 As[128 * 64];
  __shared__ __bf16 Bs[128 * 64];

  const int t = threadIdx.x;
  const int wv = t >> 6, ln = t & 63;
  const int lc = ln & 15, kg = (ln >> 4) * 8;
  const int wm = wv >> 1, wn = wv & 1;
  const int L = xcd_swizzle(blockIdx.x, gridDim.x);
  const int mt = L / nxt, nt = L - mt * nxt;
  const int m0 = mt * 128, n0 = nt * 128;

  const __bf16* ga = A + (size_t)(m0 + wv * 8 + (ln >> 3)) * K + (ln & 7) * 8;
  const __bf16* gb = Bt + (size_t)(n0 + wv * 8 + (ln >> 3)) * K + (ln & 7) * 8;

  f32x4 acc[4][4] = {};

  for (int kt = 0; kt < K; kt += 64) {
#pragma unroll
    for (int i = 0; i < 4; ++i) {
      gload16(ga + (size_t)(i * 32) * K + kt, As + (i * 32 + wv * 8) * 64);
      gload16(gb + (size_t)(i * 32) * K + kt, Bs + (i * 32 + wv * 8) * 64);
    }
    __syncthreads();
#pragma unroll
    for (int ks = 0; ks < 2; ++ks) {
      bf16x8 af[4], bb[4];
#pragma unroll
      for (int m = 0; m < 4; ++m)
        af[m] = *(const bf16x8*)&As[(wm * 64 + m * 16 + lc) * 64 + ks * 32 + kg];
#pragma unroll
      for (int n = 0; n < 4; ++n)
        bb[n] = *(const bf16x8*)&Bs[(wn * 64 + n * 16 + lc) * 64 + ks * 32 + kg];
#pragma unroll
      for (int m = 0; m < 4; ++m)
#pragma unroll
        for (int n = 0; n < 4; ++n)
          acc[m][n] = __builtin_amdgcn_mfma_f32_16x16x32_bf16(af[m], bb[n], acc[m][n], 0, 0, 0);
    }
    __syncthreads();
  }

  OT* outs[3] = {O0, O1, O2};
#pragma unroll
  for (int n = 0; n < 4; ++n) {
    int col = n0 + wn * 64 + n * 16 + lc;
    int sel = col / NoutPer;
    int c = col - sel * NoutPer;
    float bv = bias[col];
    OT* op = outs[sel];
#pragma unroll
    for (int m = 0; m < 4; ++m) {
      int row = m0 + wm * 64 + m * 16 + (ln >> 4) * 4;
#pragma unroll
      for (int r = 0; r < 4; ++r)
        op[(size_t)(row + r) * NoutPer + c] = (OT)(acc[m][n][r] + bv);
    }
  }
}

// ---- fallback GEMM (f32/bf16 A reg-staged, optional qperm) ----
template <typename AT, typename OT>
__global__ __launch_bounds__(256) void gemm_bt(
    const AT* __restrict__ A, const float* __restrict__ Bt,
    const float* __restrict__ bias,
    OT* __restrict__ O0, OT* __restrict__ O1, OT* __restrict__ O2,
    int K, int NoutPer, int qPerm, int nxt) {
  __shared__ __bf16 As[128 * 64];
  __shared__ __bf16 Bs[128 * 64];

  const int t = threadIdx.x;
  const int wv = t >> 6, ln = t & 63;
  const int lc = ln & 15, kg = (ln >> 4) * 8;
  const int wm = wv >> 1, wn = wv & 1;
  const int L = xcd_swizzle(blockIdx.x, gridDim.x);
  const int mt = L / nxt, nt = L - mt * nxt;
  const int m0 = mt * 128, n0 = nt * 128;
  const int srow = t >> 3, scol = (t & 7) * 8;

  f32x4 acc[4][4] = {};

  for (int kt = 0; kt < K; kt += 64) {
#pragma unroll
    for (int i = 0; i < 4; ++i) {
      int row = i * 32 + srow;
      *(bf16x8*)&As[row * 64 + scol] = load8_cvt(A + (size_t)(m0 + row) * K + kt + scol);
      *(bf16x8*)&Bs[row * 64 + scol] = load8_cvt(Bt + (size_t)(n0 + row) * K + kt + scol);
    }
    __syncthreads();
#pragma unroll
    for (int ks = 0; ks < 2; ++ks) {
      bf16x8 af[4], bb[4];
#pragma unroll
      for (int m = 0; m < 4; ++m)
        af[m] = *(const bf16x8*)&As[(wm * 64 + m * 16 + lc) * 64 + ks * 32 + kg];
#pragma unroll
      for (int n = 0; n < 4; ++n)
        bb[n] = *(const bf16x8*)&Bs[(wn * 64 + n * 16 + lc) * 64 + ks * 32 + kg];
#pragma unroll
      for (int m = 0; m < 4; ++m)
#pragma unroll
        for (int n = 0; n < 4; ++n)
          acc[m][n] = __builtin_amdgcn_mfma_f32_16x16x32_bf16(af[m], bb[n], acc[m][n], 0, 0, 0);
    }
    __syncthreads();
  }

  OT* outs[3] = {O0, O1, O2};
#pragma unroll
  for (int n = 0; n < 4; ++n) {
    int col = n0 + wn * 64 + n * 16 + lc;
    int sel = col / NoutPer;
    int c = col - sel * NoutPer;
    float bv = bias[col];
    OT* op = outs[sel];
    bool perm = qPerm && (sel == 0);
#pragma unroll
    for (int m = 0; m < 4; ++m) {
      int row = m0 + wm * 64 + m * 16 + (ln >> 4) * 4;
#pragma unroll
      for (int r = 0; r < 4; ++r) {
        int rr = row + r;
        int orow = perm ? qperm(rr) : rr;
        op[(size_t)orow * NoutPer + c] = (OT)(acc[m][n][r] + bv);
      }
    }
  }
}

// ---- attention: one block per (window, head), 4 waves, 32.4 KB LDS ----
// QPIX=1: Qg pixel-ordered (offset via TOKTAB); QPIX=0: Qg window-ordered.
// Og always window-ordered (rows win*49+q).
template <int QPIX>
__global__ __launch_bounds__(256, 5) void attn_win(
    const __bf16* __restrict__ Qg, const __bf16* __restrict__ Kg, const __bf16* __restrict__ Vg,
    const float* __restrict__ rpbT, const float* __restrict__ rpbN,
    __bf16* __restrict__ Og) {
  __shared__ __bf16 smem[9800 + 32 * 200];
  __bf16* Ks = smem;           // [192][40]
  __bf16* Ps = smem;           // [49][200] rotated, aliases Ks after QK^T
  __bf16* Vt = smem + 9800;    // [32][200] rotated

  const int L = xcd_swizzle(blockIdx.x, NWIN * NHEAD);
  const int win = L / NHEAD, h = L - win * NHEAD;
  const int b = win / (NWY * NWX);
  const int wrem = win - b * (NWY * NWX);
  const int wy = wrem / NWX, wx = wrem - wy * NWX;
  const int y0 = wy * WSZ, x0 = wx * WSZ;

  const int t = threadIdx.x;
  const int wv = t >> 6, ln = t & 63;
  const int lc = ln & 15, lg = ln >> 4;
  const int hb = h * HDIM;

  // Q fragment straight from global
  bf16x8 aq = {};
  {
    int qrow = wv * 16 + lc;
    if (qrow < WS2) {
      size_t qoff;
      if (QPIX) {
        int pk = TOKTAB.v[qrow];
        int yy = y0 + (pk >> 5) - 8, xx = x0 + (pk & 31) - 8;
        qoff = (size_t)((b * HH + yy) * WW + xx) * DIM;
      } else {
        qoff = (size_t)(win * WS2 + qrow) * DIM;
      }
      aq = *(const bf16x8*)(Qg + qoff + hb + lg * 8);
    }
  }

  // stage K (row-major, stride 40) and V^T (rotated): 192 tokens x 4 chunks
#pragma unroll
  for (int it = 0; it < 3; ++it) {
    int idx = t + it * 256;
    int token = idx >> 2, ch = idx & 3;
    int pk = TOKTAB.v[token];
    int yy = y0 + (pk >> 5) - 8;
    int xx = x0 + (pk & 31) - 8;
    if (yy < 0) yy += HH; else if (yy >= HH) yy -= HH;
    if (xx < 0) xx += WW; else if (xx >= WW) xx -= WW;
    size_t off = (size_t)((b * HH + yy) * WW + xx) * DIM + hb + ch * 8;
    bf16x8 kv = {}, vv = {};
    if (token < NTOK) {
      kv = *(const bf16x8*)(Kg + off);
      vv = *(const bf16x8*)(Vg + off);
    }
    *(bf16x8*)&Ks[token * 40 + ch * 8] = kv;
    int col2 = token + ch * 16; if (col2 >= 200) col2 -= 200;
#pragma unroll
    for (int e = 0; e < 8; ++e)
      Vt[(ch * 8 + e) * 200 + col2] = vv[e];
  }
  __syncthreads();

  // QK^T
  f32x4 s[12];
#pragma unroll
  for (int nf = 0; nf < 12; ++nf) {
    bf16x8 bk = *(const bf16x8*)&Ks[(nf * 16 + lc) * 40 + lg * 8];
    f32x4 z = {};
    s[nf] = __builtin_amdgcn_mfma_f32_16x16x32_bf16(aq, bk, z, 0, 0, 0);
  }
  __syncthreads();  // Ks reads complete before Ps overwrites the region

  // scale + bias (+ additive mask for pad cols), then row softmax
  float p[12][4];
  float mx[4] = {-60.f, -60.f, -60.f, -60.f};
#pragma unroll
  for (int nf = 0; nf < 12; ++nf) {
    int kcol = nf * 16 + lc;
    int kc = min(kcol, NTOK - 1);
    float kmask = (kcol < NTOK) ? 0.f : -60.f;
    int ik = kc / 7, jk = kc - ik * 7;
#pragma unroll
    for (int r = 0; r < 4; ++r) {
      int q = wv * 16 + lg * 4 + r;
      int qc = min(q, WS2 - 1);
      float bvs;
      if (kcol < WS2) {
        int iq = qc / 7, jq = qc - iq * 7;
        bvs = rpbT[((iq - ik + 6) * 13 + (jq - jk + 6)) * NHEAD + h];
      } else {
        bvs = rpbN[(h * WS2 + qc) * NKEY + (kc - WS2)];
      }
      float val = s[nf][r] * SCALE + bvs + kmask;
      p[nf][r] = val;
      mx[r] = fmaxf(mx[r], val);
    }
  }
#pragma unroll
  for (int d = 1; d < 16; d <<= 1)
#pragma unroll
    for (int r = 0; r < 4; ++r) mx[r] = fmaxf(mx[r], __shfl_xor(mx[r], d));

  float sm[4] = {0.f, 0.f, 0.f, 0.f};
#pragma unroll
  for (int nf = 0; nf < 12; ++nf)
#pragma unroll
    for (int r = 0; r < 4; ++r) { p[nf][r] = __expf(p[nf][r] - mx[r]); sm[r] += p[nf][r]; }
#pragma unroll
  for (int d = 1; d < 16; d <<= 1)
#pragma unroll
    for (int r = 0; r < 4; ++r) sm[r] += __shfl_xor(sm[r], d);

  float inv[4];
#pragma unroll
  for (int r = 0; r < 4; ++r) inv[r] = 1.0f / sm[r];

#pragma unroll
  for (int nf = 0; nf < 12; ++nf) {
    int kcol = nf * 16 + lc;
#pragma unroll
    for (int r = 0; r < 4; ++r) {
      int q = wv * 16 + lg * 4 + r;
      if (q < WS2) {
        int c2 = kcol + ((q >> 3) & 1) * 16; if (c2 >= 200) c2 -= 200;
        Ps[q * 200 + c2] = (__bf16)(p[nf][r] * inv[r]);
      }
    }
  }
  __syncthreads();

  // PV
  f32x4 o[2] = {{}, {}};
  const int rowP = wv * 16 + lc;
  const int rotP = ((lc >> 3) & 1) * 16;
#pragma unroll
  for (int ks = 0; ks < 6; ++ks) {
    int c0 = ks * 32 + lg * 8 + rotP; if (c0 >= 200) c0 -= 200;
    bf16x8 ap = *(const bf16x8*)&Ps[rowP * 200 + c0];
#pragma unroll
    for (int nf = 0; nf < 2; ++nf) {
      int rowV = nf * 16 + lc;
      int cv = ks * 32 + lg * 8 + (rowV >> 3) * 16; if (cv >= 200) cv -= 200;
      bf16x8 bv = *(const bf16x8*)&Vt[rowV * 200 + cv];
      o[nf] = __builtin_amdgcn_mfma_f32_16x16x32_bf16(ap, bv, o[nf], 0, 0, 0);
    }
  }

#pragma unroll
  for (int nf = 0; nf < 2; ++nf)
#pragma unroll
    for (int r = 0; r < 4; ++r) {
      int q = wv * 16 + lg * 4 + r;
      if (q < WS2)
        Og[(size_t)(win * WS2 + q) * DIM + hb + nf * 16 + lc] = (__bf16)(o[nf][r]);
    }
}

extern "C" void kernel_launch(void* const* d_in, const int* in_sizes, int n_in,
                              void* d_out, int out_size, void* d_ws, size_t ws_size,
                              hipStream_t stream) {
  const float* x      = (const float*)d_in[0];
  const float* w_qkv  = (const float*)d_in[1];
  const float* b_qkv  = (const float*)d_in[2];
  const float* w_proj = (const float*)d_in[3];
  const float* b_proj = (const float*)d_in[4];
  const float* rpbT   = (const float*)d_in[5];
  const float* rpbN   = (const float*)d_in[6];

  float* out = (float*)d_out;
  __bf16* k_ws = (__bf16*)d_out;           // d_out = 2 bf16 planes (K, V)
  __bf16* v_ws = k_ws + PLANE;

  const size_t fast_ws_bytes = (2 * PLANE + NQKV + NPROJ) * sizeof(__bf16);  // 87.9 MB

  if (ws_size >= fast_ws_bytes) {
    // FAST PATH: pre-convert to bf16, global_load_lds GEMMs, no row permute.
    __bf16* xo_bf  = (__bf16*)d_ws;        // x_bf during gemm1; O plane after
    __bf16* q_bf   = xo_bf + PLANE;        // Q, pixel-ordered
    __bf16* wqkv_b = q_bf + PLANE;
    __bf16* wproj_b = wqkv_b + NQKV;

    cvt3<<<dim3(CVT_GRID), 256, 0, stream>>>(x, w_qkv, w_proj, xo_bf, wqkv_b, wproj_b);

    gemm_fast<__bf16><<<dim3((1152 / 128) * (MTOT / 128)), 256, 0, stream>>>(
        xo_bf, wqkv_b, b_qkv, q_bf, k_ws, v_ws, DIM, DIM, 1152 / 128);

    attn_win<1><<<dim3(NWIN * NHEAD), 256, 0, stream>>>(
        q_bf, k_ws, v_ws, rpbT, rpbN, xo_bf);   // O overwrites dead x_bf

    gemm_fast<float><<<dim3((384 / 128) * (MTOT / 128)), 256, 0, stream>>>(
        xo_bf, wproj_b, b_proj, out, out, out, DIM, DIM, 384 / 128);
  } else {
    // FALLBACK (round-5 path): f32 reg-staged GEMM1 with qperm epilogue.
    __bf16* qo_ws = (__bf16*)d_ws;

    gemm_bt<float, __bf16><<<dim3((1152 / 128) * (MTOT / 128)), 256, 0, stream>>>(
        x, w_qkv, b_qkv, qo_ws, k_ws, v_ws, DIM, DIM, 1, 1152 / 128);

    attn_win<0><<<dim3(NWIN * NHEAD), 256, 0, stream>>>(
        qo_ws, k_ws, v_ws, rpbT, rpbN, qo_ws);

    gemm_bt<__bf16, float><<<dim3((384 / 128) * (MTOT / 128)), 256, 0, stream>>>(
        qo_ws, w_proj, b_proj, out, out, out, DIM, DIM, 0, 384 / 128);
  }
}

// Round 7
// 286.425 us; speedup vs baseline: 2.0977x; 1.1693x over previous
//
#include <hip/hip_runtime.h>
#include <hip/hip_bf16.h>
#include <stdint.h>

typedef __attribute__((ext_vector_type(8))) __bf16 bf16x8;
typedef __attribute__((ext_vector_type(4))) float f32x4;

#define DEVINL static __device__ __forceinline__

constexpr int WSZ = 7, EXPAND = 3, NHEAD = 12, DIM = 384, HDIM = 32;
constexpr int WS2 = 49, NKEY = 132, NTOK = 181;
constexpr int BB = 2, HH = 168, WW = 168;
constexpr int NWY = HH / WSZ, NWX = WW / WSZ;        // 24, 24
constexpr int NWIN = BB * NWY * NWX;                 // 1152
constexpr int MTOT = BB * HH * WW;                   // 56448
constexpr float SCALE = 0.1767766952966369f;         // 32^-0.5
constexpr size_t PLANE = (size_t)MTOT * DIM;         // 21,676,032
constexpr int NQKV = 3 * DIM * DIM;                  // 442,368
constexpr int NPROJ = DIM * DIM;                     // 147,456
constexpr int BIAS_ELEMS = NHEAD * 192 * 64;         // 147,456 f32 (590 KB)

// ---- packed token offset table: (dy+8)<<5 | (dx+8), window-relative ----
struct TokTab { int v[192]; };
constexpr TokTab make_toktab() {
  TokTab tt{};
  for (int t = 0; t < 192; ++t) tt.v[t] = 8 * 32 + 8;
  for (int t = 0; t < WS2; ++t) tt.v[t] = (t / WSZ + 8) * 32 + (t % WSZ + 8);
  int n = WS2;
  for (int quad = 0; quad < 4; ++quad)
    for (int i = 0; i < WSZ; ++i)
      for (int j = 0; j < WSZ; ++j) {
        bool drop;
        if (quad == 0)      drop = (i < WSZ - EXPAND) && (j < WSZ - EXPAND);
        else if (quad == 1) drop = (i < WSZ - EXPAND) && (j >= EXPAND);
        else if (quad == 2) drop = (i >= EXPAND)      && (j < WSZ - EXPAND);
        else                drop = (i >= EXPAND)      && (j >= EXPAND);
        if (!drop) {
          int dy = (quad < 2)        ? i + EXPAND : i - EXPAND;
          int dx = ((quad & 1) == 0) ? j + EXPAND : j - EXPAND;
          tt.v[n++] = (dy + 8) * 32 + (dx + 8);
        }
      }
  return tt;
}
__device__ constexpr TokTab TOKTAB = make_toktab();

DEVINL int xcd_swizzle(int bid, int nwg) {
  int q8 = nwg >> 3, r8 = nwg & 7;
  int xcd = bid & 7, ii = bid >> 3;
  return (xcd < r8 ? xcd * (q8 + 1) : r8 * (q8 + 1) + (xcd - r8) * q8) + ii;
}

// pixel-row -> window-ordered row permutation (fallback path only)
DEVINL int qperm(int m) {
  int b = m / (HH * WW);
  int rem = m - b * (HH * WW);
  int y = rem / WW;
  int x = rem - y * WW;
  int win = b * (NWY * NWX) + (y / WSZ) * NWX + (x / WSZ);
  int qi = (y % WSZ) * WSZ + (x % WSZ);
  return win * WS2 + qi;
}

DEVINL bf16x8 load8_cvt(const float* p) {
  float4 a = *(const float4*)p;
  float4 b = *(const float4*)(p + 4);
  bf16x8 r = {(__bf16)a.x, (__bf16)a.y, (__bf16)a.z, (__bf16)a.w,
              (__bf16)b.x, (__bf16)b.y, (__bf16)b.z, (__bf16)b.w};
  return r;
}
DEVINL bf16x8 load8_cvt(const __bf16* p) { return *(const bf16x8*)p; }

DEVINL void gload16(const __bf16* g, __bf16* l) {
  __builtin_amdgcn_global_load_lds(
      (const __attribute__((address_space(1))) unsigned int*)g,
      (__attribute__((address_space(3))) unsigned int*)l, 16, 0, 0);
}

// ---- fused: f32->bf16 convert (x, w_qkv, w_proj) + bias table build ----
// biasTab layout [h][k(192)][q(64)] f32: pad k>=181 -> -60 (key mask),
// pad q>=49 -> 0. Makes attn's bias = one float4 load + FMA.
constexpr int XG8 = PLANE / 8;            // 2,709,504
constexpr int QG8 = NQKV / 8;             // 55,296
constexpr int PG8 = NPROJ / 8;            // 18,432
constexpr int CVT_GRID = (XG8 + QG8 + PG8) / 256;  // 10,872 exact
constexpr int BIAS_GRID = BIAS_ELEMS / 256;        // 576

__global__ __launch_bounds__(256) void cvt_bias(
    const float* __restrict__ a, const float* __restrict__ b, const float* __restrict__ c,
    __bf16* __restrict__ da, __bf16* __restrict__ db, __bf16* __restrict__ dc,
    const float* __restrict__ rpbT, const float* __restrict__ rpbN,
    float* __restrict__ biasTab, int cvtBlocks) {
  int bid = blockIdx.x;
  if (bid < cvtBlocks) {
    int i = bid * 256 + threadIdx.x;
    const float* s; __bf16* d; int j;
    if (i < XG8)            { s = a; d = da; j = i; }
    else if (i < XG8 + QG8) { s = b; d = db; j = i - XG8; }
    else                    { s = c; d = dc; j = i - XG8 - QG8; }
    *(bf16x8*)(d + (size_t)j * 8) = load8_cvt(s + (size_t)j * 8);
  } else {
    int i = (bid - cvtBlocks) * 256 + threadIdx.x;   // ((h*192)+k)*64+q
    int q = i & 63;
    int rest = i >> 6;
    int k = rest % 192, h = rest / 192;
    float v = 0.f;
    if (k >= NTOK) v = -60.f;
    else if (q < WS2) {
      if (k < WS2) {
        int iq = q / 7, jq = q - iq * 7, ik = k / 7, jk = k - ik * 7;
        v = rpbT[((iq - ik + 6) * 13 + (jq - jk + 6)) * NHEAD + h];
      } else {
        v = rpbN[(h * WS2 + q) * NKEY + (k - WS2)];
      }
    }
    biasTab[i] = v;
  }
}

// ---- fast GEMM (bf16 A and Bt, global_load_lds staging, m97 structure) ----
template <typename OT>
__global__ __launch_bounds__(256) void gemm_fast(
    const __bf16* __restrict__ A, const __bf16* __restrict__ Bt,
    const float* __restrict__ bias,
    OT* __restrict__ O0, OT* __restrict__ O1, OT* __restrict__ O2,
    int K, int NoutPer, int nxt) {
  __shared__ __bf16 As[128 * 64];
  __shared__ __bf16 Bs[128 * 64];

  const int t = threadIdx.x;
  const int wv = t >> 6, ln = t & 63;
  const int lc = ln & 15, kg = (ln >> 4) * 8;
  const int wm = wv >> 1, wn = wv & 1;
  const int L = xcd_swizzle(blockIdx.x, gridDim.x);
  const int mt = L / nxt, nt = L - mt * nxt;
  const int m0 = mt * 128, n0 = nt * 128;

  const __bf16* ga = A + (size_t)(m0 + wv * 8 + (ln >> 3)) * K + (ln & 7) * 8;
  const __bf16* gb = Bt + (size_t)(n0 + wv * 8 + (ln >> 3)) * K + (ln & 7) * 8;

  f32x4 acc[4][4] = {};

  for (int kt = 0; kt < K; kt += 64) {
#pragma unroll
    for (int i = 0; i < 4; ++i) {
      gload16(ga + (size_t)(i * 32) * K + kt, As + (i * 32 + wv * 8) * 64);
      gload16(gb + (size_t)(i * 32) * K + kt, Bs + (i * 32 + wv * 8) * 64);
    }
    __syncthreads();
#pragma unroll
    for (int ks = 0; ks < 2; ++ks) {
      bf16x8 af[4], bb[4];
#pragma unroll
      for (int m = 0; m < 4; ++m)
        af[m] = *(const bf16x8*)&As[(wm * 64 + m * 16 + lc) * 64 + ks * 32 + kg];
#pragma unroll
      for (int n = 0; n < 4; ++n)
        bb[n] = *(const bf16x8*)&Bs[(wn * 64 + n * 16 + lc) * 64 + ks * 32 + kg];
#pragma unroll
      for (int m = 0; m < 4; ++m)
#pragma unroll
        for (int n = 0; n < 4; ++n)
          acc[m][n] = __builtin_amdgcn_mfma_f32_16x16x32_bf16(af[m], bb[n], acc[m][n], 0, 0, 0);
    }
    __syncthreads();
  }

  OT* outs[3] = {O0, O1, O2};
#pragma unroll
  for (int n = 0; n < 4; ++n) {
    int col = n0 + wn * 64 + n * 16 + lc;
    int sel = col / NoutPer;
    int c = col - sel * NoutPer;
    float bv = bias[col];
    OT* op = outs[sel];
#pragma unroll
    for (int m = 0; m < 4; ++m) {
      int row = m0 + wm * 64 + m * 16 + (ln >> 4) * 4;
#pragma unroll
      for (int r = 0; r < 4; ++r)
        op[(size_t)(row + r) * NoutPer + c] = (OT)(acc[m][n][r] + bv);
    }
  }
}

// ---- fallback GEMM (f32/bf16 A reg-staged, optional qperm) ----
template <typename AT, typename OT>
__global__ __launch_bounds__(256) void gemm_bt(
    const AT* __restrict__ A, const float* __restrict__ Bt,
    const float* __restrict__ bias,
    OT* __restrict__ O0, OT* __restrict__ O1, OT* __restrict__ O2,
    int K, int NoutPer, int qPerm, int nxt) {
  __shared__ __bf16 As[128 * 64];
  __shared__ __bf16 Bs[128 * 64];

  const int t = threadIdx.x;
  const int wv = t >> 6, ln = t & 63;
  const int lc = ln & 15, kg = (ln >> 4) * 8;
  const int wm = wv >> 1, wn = wv & 1;
  const int L = xcd_swizzle(blockIdx.x, gridDim.x);
  const int mt = L / nxt, nt = L - mt * nxt;
  const int m0 = mt * 128, n0 = nt * 128;
  const int srow = t >> 3, scol = (t & 7) * 8;

  f32x4 acc[4][4] = {};

  for (int kt = 0; kt < K; kt += 64) {
#pragma unroll
    for (int i = 0; i < 4; ++i) {
      int row = i * 32 + srow;
      *(bf16x8*)&As[row * 64 + scol] = load8_cvt(A + (size_t)(m0 + row) * K + kt + scol);
      *(bf16x8*)&Bs[row * 64 + scol] = load8_cvt(Bt + (size_t)(n0 + row) * K + kt + scol);
    }
    __syncthreads();
#pragma unroll
    for (int ks = 0; ks < 2; ++ks) {
      bf16x8 af[4], bb[4];
#pragma unroll
      for (int m = 0; m < 4; ++m)
        af[m] = *(const bf16x8*)&As[(wm * 64 + m * 16 + lc) * 64 + ks * 32 + kg];
#pragma unroll
      for (int n = 0; n < 4; ++n)
        bb[n] = *(const bf16x8*)&Bs[(wn * 64 + n * 16 + lc) * 64 + ks * 32 + kg];
#pragma unroll
      for (int m = 0; m < 4; ++m)
#pragma unroll
        for (int n = 0; n < 4; ++n)
          acc[m][n] = __builtin_amdgcn_mfma_f32_16x16x32_bf16(af[m], bb[n], acc[m][n], 0, 0, 0);
    }
    __syncthreads();
  }

  OT* outs[3] = {O0, O1, O2};
#pragma unroll
  for (int n = 0; n < 4; ++n) {
    int col = n0 + wn * 64 + n * 16 + lc;
    int sel = col / NoutPer;
    int c = col - sel * NoutPer;
    float bv = bias[col];
    OT* op = outs[sel];
    bool perm = qPerm && (sel == 0);
#pragma unroll
    for (int m = 0; m < 4; ++m) {
      int row = m0 + wm * 64 + m * 16 + (ln >> 4) * 4;
#pragma unroll
      for (int r = 0; r < 4; ++r) {
        int rr = row + r;
        int orow = perm ? qperm(rr) : rr;
        op[(size_t)orow * NoutPer + c] = (OT)(acc[m][n][r] + bv);
      }
    }
  }
}

// ---- attention: one block per (window, head), 4 waves, 32.4 KB LDS ----
// QPIX=1: Qg pixel-ordered (offset via TOKTAB); QPIX=0: Qg window-ordered.
// Og always window-ordered. Bias via precomputed [h][k][64] table.
template <int QPIX>
__global__ __launch_bounds__(256, 5) void attn_win(
    const __bf16* __restrict__ Qg, const __bf16* __restrict__ Kg, const __bf16* __restrict__ Vg,
    const float* __restrict__ biasTab,
    __bf16* __restrict__ Og) {
  __shared__ __bf16 smem[9800 + 32 * 200];
  __bf16* Ks = smem;           // [192][40]
  __bf16* Ps = smem;           // [49][200] rotated, aliases Ks after QK^T
  __bf16* Vt = smem + 9800;    // [32][200] rotated

  const int L = xcd_swizzle(blockIdx.x, NWIN * NHEAD);
  const int win = L / NHEAD, h = L - win * NHEAD;
  const int b = win / (NWY * NWX);
  const int wrem = win - b * (NWY * NWX);
  const int wy = wrem / NWX, wx = wrem - wy * NWX;
  const int y0 = wy * WSZ, x0 = wx * WSZ;

  const int t = threadIdx.x;
  const int wv = t >> 6, ln = t & 63;
  const int lc = ln & 15, lg = ln >> 4;
  const int hb = h * HDIM;

  // Q fragment straight from global
  bf16x8 aq = {};
  {
    int qrow = wv * 16 + lc;
    if (qrow < WS2) {
      size_t qoff;
      if (QPIX) {
        int pk = TOKTAB.v[qrow];
        int yy = y0 + (pk >> 5) - 8, xx = x0 + (pk & 31) - 8;
        qoff = (size_t)((b * HH + yy) * WW + xx) * DIM;
      } else {
        qoff = (size_t)(win * WS2 + qrow) * DIM;
      }
      aq = *(const bf16x8*)(Qg + qoff + hb + lg * 8);
    }
  }

  // stage K (row-major, stride 40) and V^T (rotated): 192 tokens x 4 chunks
#pragma unroll
  for (int it = 0; it < 3; ++it) {
    int idx = t + it * 256;
    int token = idx >> 2, ch = idx & 3;
    int pk = TOKTAB.v[token];
    int yy = y0 + (pk >> 5) - 8;
    int xx = x0 + (pk & 31) - 8;
    if (yy < 0) yy += HH; else if (yy >= HH) yy -= HH;
    if (xx < 0) xx += WW; else if (xx >= WW) xx -= WW;
    size_t off = (size_t)((b * HH + yy) * WW + xx) * DIM + hb + ch * 8;
    bf16x8 kv = {}, vv = {};
    if (token < NTOK) {
      kv = *(const bf16x8*)(Kg + off);
      vv = *(const bf16x8*)(Vg + off);
    }
    *(bf16x8*)&Ks[token * 40 + ch * 8] = kv;
    int col2 = token + ch * 16; if (col2 >= 200) col2 -= 200;
#pragma unroll
    for (int e = 0; e < 8; ++e)
      Vt[(ch * 8 + e) * 200 + col2] = vv[e];
  }
  __syncthreads();

  // QK^T
  f32x4 s[12];
  __builtin_amdgcn_s_setprio(1);
#pragma unroll
  for (int nf = 0; nf < 12; ++nf) {
    bf16x8 bk = *(const bf16x8*)&Ks[(nf * 16 + lc) * 40 + lg * 8];
    f32x4 z = {};
    s[nf] = __builtin_amdgcn_mfma_f32_16x16x32_bf16(aq, bk, z, 0, 0, 0);
  }
  __builtin_amdgcn_s_setprio(0);
  __syncthreads();  // Ks reads complete before Ps overwrites the region

  // bias from precomputed table (one float4 per nf) + row softmax
  const float* btab = biasTab + (size_t)h * (192 * 64) + wv * 16 + lg * 4;
  float p[12][4];
  float mx[4] = {-60.f, -60.f, -60.f, -60.f};
#pragma unroll
  for (int nf = 0; nf < 12; ++nf) {
    f32x4 bt = *(const f32x4*)&btab[(nf * 16 + lc) * 64];
#pragma unroll
    for (int r = 0; r < 4; ++r) {
      float val = fmaf(s[nf][r], SCALE, bt[r]);
      p[nf][r] = val;
      mx[r] = fmaxf(mx[r], val);
    }
  }
#pragma unroll
  for (int d = 1; d < 16; d <<= 1)
#pragma unroll
    for (int r = 0; r < 4; ++r) mx[r] = fmaxf(mx[r], __shfl_xor(mx[r], d));

  float sm[4] = {0.f, 0.f, 0.f, 0.f};
#pragma unroll
  for (int nf = 0; nf < 12; ++nf)
#pragma unroll
    for (int r = 0; r < 4; ++r) { p[nf][r] = __expf(p[nf][r] - mx[r]); sm[r] += p[nf][r]; }
#pragma unroll
  for (int d = 1; d < 16; d <<= 1)
#pragma unroll
    for (int r = 0; r < 4; ++r) sm[r] += __shfl_xor(sm[r], d);

  float inv[4];
#pragma unroll
  for (int r = 0; r < 4; ++r) inv[r] = 1.0f / sm[r];

#pragma unroll
  for (int nf = 0; nf < 12; ++nf) {
    int kcol = nf * 16 + lc;
#pragma unroll
    for (int r = 0; r < 4; ++r) {
      int q = wv * 16 + lg * 4 + r;
      if (q < WS2) {
        int c2 = kcol + ((q >> 3) & 1) * 16; if (c2 >= 200) c2 -= 200;
        Ps[q * 200 + c2] = (__bf16)(p[nf][r] * inv[r]);
      }
    }
  }
  __syncthreads();

  // PV
  f32x4 o[2] = {{}, {}};
  const int rowP = wv * 16 + lc;
  const int rotP = ((lc >> 3) & 1) * 16;
  __builtin_amdgcn_s_setprio(1);
#pragma unroll
  for (int ks = 0; ks < 6; ++ks) {
    int c0 = ks * 32 + lg * 8 + rotP; if (c0 >= 200) c0 -= 200;
    bf16x8 ap = *(const bf16x8*)&Ps[rowP * 200 + c0];
#pragma unroll
    for (int nf = 0; nf < 2; ++nf) {
      int rowV = nf * 16 + lc;
      int cv = ks * 32 + lg * 8 + (rowV >> 3) * 16; if (cv >= 200) cv -= 200;
      bf16x8 bv = *(const bf16x8*)&Vt[rowV * 200 + cv];
      o[nf] = __builtin_amdgcn_mfma_f32_16x16x32_bf16(ap, bv, o[nf], 0, 0, 0);
    }
  }
  __builtin_amdgcn_s_setprio(0);

#pragma unroll
  for (int nf = 0; nf < 2; ++nf)
#pragma unroll
    for (int r = 0; r < 4; ++r) {
      int q = wv * 16 + lg * 4 + r;
      if (q < WS2)
        Og[(size_t)(win * WS2 + q) * DIM + hb + nf * 16 + lc] = (__bf16)(o[nf][r]);
    }
}

extern "C" void kernel_launch(void* const* d_in, const int* in_sizes, int n_in,
                              void* d_out, int out_size, void* d_ws, size_t ws_size,
                              hipStream_t stream) {
  const float* x      = (const float*)d_in[0];
  const float* w_qkv  = (const float*)d_in[1];
  const float* b_qkv  = (const float*)d_in[2];
  const float* w_proj = (const float*)d_in[3];
  const float* b_proj = (const float*)d_in[4];
  const float* rpbT   = (const float*)d_in[5];
  const float* rpbN   = (const float*)d_in[6];

  float* out = (float*)d_out;
  __bf16* k_ws = (__bf16*)d_out;           // d_out = 2 bf16 planes (K, V)
  __bf16* v_ws = k_ws + PLANE;

  const size_t fast_elems = 2 * PLANE + NQKV + NPROJ;
  const size_t fast_ws_bytes = fast_elems * 2 + BIAS_ELEMS * 4;   // ~88.5 MB
  const size_t fb_ws_bytes = PLANE * 2 + BIAS_ELEMS * 4;

  if (ws_size >= fast_ws_bytes) {
    // FAST PATH: pre-convert to bf16, global_load_lds GEMMs, no row permute.
    __bf16* xo_bf   = (__bf16*)d_ws;       // x_bf during gemm1; O plane after
    __bf16* q_bf    = xo_bf + PLANE;       // Q, pixel-ordered
    __bf16* wqkv_b  = q_bf + PLANE;
    __bf16* wproj_b = wqkv_b + NQKV;
    float*  biasTab = (float*)(wproj_b + NPROJ);

    cvt_bias<<<dim3(CVT_GRID + BIAS_GRID), 256, 0, stream>>>(
        x, w_qkv, w_proj, xo_bf, wqkv_b, wproj_b, rpbT, rpbN, biasTab, CVT_GRID);

    gemm_fast<__bf16><<<dim3((1152 / 128) * (MTOT / 128)), 256, 0, stream>>>(
        xo_bf, wqkv_b, b_qkv, q_bf, k_ws, v_ws, DIM, DIM, 1152 / 128);

    attn_win<1><<<dim3(NWIN * NHEAD), 256, 0, stream>>>(
        q_bf, k_ws, v_ws, biasTab, xo_bf);   // O overwrites dead x_bf

    gemm_fast<float><<<dim3((384 / 128) * (MTOT / 128)), 256, 0, stream>>>(
        xo_bf, wproj_b, b_proj, out, out, out, DIM, DIM, 384 / 128);
  } else {
    // FALLBACK: f32 reg-staged GEMM1 with qperm epilogue.
    __bf16* qo_ws   = (__bf16*)d_ws;
    float*  biasTab = (float*)(qo_ws + PLANE);

    cvt_bias<<<dim3(BIAS_GRID), 256, 0, stream>>>(
        x, w_qkv, w_proj, nullptr, nullptr, nullptr, rpbT, rpbN, biasTab, 0);

    gemm_bt<float, __bf16><<<dim3((1152 / 128) * (MTOT / 128)), 256, 0, stream>>>(
        x, w_qkv, b_qkv, qo_ws, k_ws, v_ws, DIM, DIM, 1, 1152 / 128);

    attn_win<0><<<dim3(NWIN * NHEAD), 256, 0, stream>>>(
        qo_ws, k_ws, v_ws, biasTab, qo_ws);

    gemm_bt<__bf16, float><<<dim3((384 / 128) * (MTOT / 128)), 256, 0, stream>>>(
        qo_ws, w_proj, b_proj, out, out, out, DIM, DIM, 0, 384 / 128);
  }
}